// Round 1
// baseline (286.087 us; speedup 1.0000x reference)
//
#include <hip/hip_runtime.h>
#include <cstdint>
#include <cstddef>

typedef unsigned short u16;
typedef unsigned int   u32;

typedef short bf16x8 __attribute__((ext_vector_type(8)));
typedef float f32x4  __attribute__((ext_vector_type(4)));

// ---------------- helpers ----------------
__device__ __forceinline__ u16 f2bf(float f) {   // RNE f32 -> bf16
  u32 u = __float_as_uint(f);
  u += 0x7fffu + ((u >> 16) & 1u);
  return (u16)(u >> 16);
}
__device__ __forceinline__ float bflo(u32 w) { return __uint_as_float((w & 0xffffu) << 16); }
__device__ __forceinline__ float bfhi(u32 w) { return __uint_as_float(w & 0xffff0000u); }

#define GLB_AS(p) ((const __attribute__((address_space(1))) void*)(p))
#define LDS_AS(p) ((__attribute__((address_space(3))) void*)(p))

// ---------------- f32 -> bf16 convert (4 elems/thread) ----------------
__global__ __launch_bounds__(256) void conv_f32_bf16(const float* __restrict__ src,
                                                     u16* __restrict__ dst, int n4) {
  int i = blockIdx.x * 256 + threadIdx.x;
  if (i >= n4) return;
  float4 v = ((const float4*)src)[i];
  u32 lo = (u32)f2bf(v.x) | ((u32)f2bf(v.y) << 16);
  u32 hi = (u32)f2bf(v.z) | ((u32)f2bf(v.w) << 16);
  ((uint2*)dst)[i] = make_uint2(lo, hi);
}

// ---------------- bf16 GEMM: C[m,n] = sum_k A[m,k] * W[n,k] (+bias, opt relu)
// A: M x K row-major bf16; W: N x K row-major bf16 (i.e. B^T form).
// Tiles: BM=BN=128, BK=32. 256 threads = 4 waves in 2x2, each wave 64x64 (4x4
// MFMA 16x16x32 tiles). Staging via global_load_lds width=16 into XOR-swizzled
// 16B granules: granule g holds data (row=g>>2, k8=(g&3)^(row&3)).
// Fragment read (m, k8=q): granule = m*4 + (q^(m&3)) -> conflict-free b128.
template<int OUT_BF16, int RELU>
__global__ __launch_bounds__(256)
void gemm_bt(const u16* __restrict__ A, const u16* __restrict__ Bw,
             const float* __restrict__ bias, void* __restrict__ Cout,
             int M, int N, int K)
{
  __shared__ __align__(16) u16 As[128 * 32];
  __shared__ __align__(16) u16 Bs[128 * 32];

  const int tid  = threadIdx.x;
  const int lane = tid & 63;
  const int wave = tid >> 6;
  const int m0 = blockIdx.x * 128;
  const int n0 = blockIdx.y * 128;
  const int wm = (wave & 1) * 64;
  const int wn = (wave >> 1) * 64;

  f32x4 acc[4][4];
#pragma unroll
  for (int i = 0; i < 4; ++i)
#pragma unroll
    for (int j = 0; j < 4; ++j) acc[i][j] = f32x4{0.f, 0.f, 0.f, 0.f};

  // staging granules: 512 per tile, 256 threads -> 2 passes each for A and B.
  const int g0 = tid;        // pass 0
  const int g1 = 256 + tid;  // pass 1
  const int r0 = g0 >> 2, c0 = (((g0 & 3) ^ (r0 & 3)) << 3);
  const int r1 = g1 >> 2, c1 = (((g1 & 3) ^ (r1 & 3)) << 3);
  const u16* Asrc0 = A  + (size_t)(m0 + r0) * K + c0;
  const u16* Asrc1 = A  + (size_t)(m0 + r1) * K + c1;
  const u16* Bsrc0 = Bw + (size_t)(n0 + r0) * K + c0;
  const u16* Bsrc1 = Bw + (size_t)(n0 + r1) * K + c1;
  // wave-uniform LDS bases (HW adds lane*16)
  u16* ldsA0 = &As[(0 * 256 + wave * 64) * 8];
  u16* ldsA1 = &As[(1 * 256 + wave * 64) * 8];
  u16* ldsB0 = &Bs[(0 * 256 + wave * 64) * 8];
  u16* ldsB1 = &Bs[(1 * 256 + wave * 64) * 8];

  // fragment granule offsets (in u16 units)
  const int fm = lane & 15;
  const int q  = lane >> 4;
  int aoff[4], boff[4];
#pragma unroll
  for (int i = 0; i < 4; ++i) {
    int ml = wm + i * 16 + fm;
    aoff[i] = (ml * 4 + (q ^ (ml & 3))) * 8;
    int nl = wn + i * 16 + fm;
    boff[i] = (nl * 4 + (q ^ (nl & 3))) * 8;
  }

  for (int k0 = 0; k0 < K; k0 += 32) {
    __builtin_amdgcn_global_load_lds(GLB_AS(Asrc0 + k0), LDS_AS(ldsA0), 16, 0, 0);
    __builtin_amdgcn_global_load_lds(GLB_AS(Asrc1 + k0), LDS_AS(ldsA1), 16, 0, 0);
    __builtin_amdgcn_global_load_lds(GLB_AS(Bsrc0 + k0), LDS_AS(ldsB0), 16, 0, 0);
    __builtin_amdgcn_global_load_lds(GLB_AS(Bsrc1 + k0), LDS_AS(ldsB1), 16, 0, 0);
    __syncthreads();  // drains vmcnt -> tile visible

    bf16x8 af[4], bfr[4];
#pragma unroll
    for (int i = 0; i < 4; ++i) af[i]  = *(const bf16x8*)&As[aoff[i]];
#pragma unroll
    for (int i = 0; i < 4; ++i) bfr[i] = *(const bf16x8*)&Bs[boff[i]];
#pragma unroll
    for (int mi = 0; mi < 4; ++mi)
#pragma unroll
      for (int ni = 0; ni < 4; ++ni)
        acc[mi][ni] = __builtin_amdgcn_mfma_f32_16x16x32_bf16(af[mi], bfr[ni],
                                                              acc[mi][ni], 0, 0, 0);
    __syncthreads();  // all reads done before next-tile DMA overwrites
  }

  // epilogue: C/D layout col=lane&15, row=(lane>>4)*4+reg
  const int colL = lane & 15;
  const int rowQ = (lane >> 4) * 4;
#pragma unroll
  for (int mi = 0; mi < 4; ++mi) {
#pragma unroll
    for (int ni = 0; ni < 4; ++ni) {
      int col  = n0 + wn + ni * 16 + colL;
      int rowb = m0 + wm + mi * 16 + rowQ;
      float bv = bias[col];
#pragma unroll
      for (int r = 0; r < 4; ++r) {
        float v = acc[mi][ni][r] + bv;
        if (RELU) v = fmaxf(v, 0.f);
        size_t idx = (size_t)(rowb + r) * N + col;
        if (OUT_BF16) ((u16*)Cout)[idx] = f2bf(v);
        else          ((float*)Cout)[idx] = v;
      }
    }
  }
}

// ---------------- scan pass 1: per-chunk end state ----------------
// u viewed as complex: channel j -> (u[...,2j], u[...,2j+1]) packed in one u32.
// chunks: 32 chunks of 128 along L. e[(b*32+c)*512+j] = local scan end.
__global__ __launch_bounds__(512)
void scan_chunk_end(const u16* __restrict__ u, const float* __restrict__ plog,
                    float2* __restrict__ e)
{
  const int j = threadIdx.x;   // channel 0..511
  const int c = blockIdx.x;    // chunk 0..31
  const int b = blockIdx.y;    // batch 0..7
  float vv  = expf(plog[j]);
  float th  = expf(plog[512 + j]);
  float mag = expf(-vv);
  float lr = mag * cosf(th), li = mag * sinf(th);
  const u32* up = (const u32*)u;
  size_t idx = (size_t)(b * 4096 + c * 128) * 512 + j;
  float hr = 0.f, hi = 0.f;
#pragma unroll 8
  for (int t = 0; t < 128; ++t) {
    u32 w = up[idx]; idx += 512;
    float ur = bflo(w), ui = bfhi(w);
    float nr = fmaf(lr, hr, fmaf(-li, hi, ur));
    float ni2 = fmaf(lr, hi, fmaf(li, hr, ui));
    hr = nr; hi = ni2;
  }
  e[(size_t)(b * 32 + c) * 512 + j] = make_float2(hr, hi);
}

// ---------------- scan pass 2: carries across chunks ----------------
__global__ __launch_bounds__(512)
void scan_carry(const float2* __restrict__ e, const float* __restrict__ plog,
                float2* __restrict__ carry)
{
  const int j = threadIdx.x;
  const int b = blockIdx.x;
  float vv = expf(plog[j]);
  float th = expf(plog[512 + j]);
  float mag = expf(-128.f * vv);
  float a = 128.f * th;
  float lr = mag * cosf(a), li = mag * sinf(a);  // lambda^128
  float Hr = 0.f, Hi = 0.f;
  for (int c = 0; c < 32; ++c) {
    size_t o = (size_t)(b * 32 + c) * 512 + j;
    carry[o] = make_float2(Hr, Hi);
    float2 ec = e[o];
    float nr = fmaf(lr, Hr, fmaf(-li, Hi, ec.x));
    float ni2 = fmaf(lr, Hi, fmaf(li, Hr, ec.y));
    Hr = nr; Hi = ni2;
  }
}

// ---------------- scan pass 3: recompute with carry, write xr (bf16) --------
// xr[b,l,j] = gamma*Re(h), xr[b,l,512+j] = gamma*Im(h)
__global__ __launch_bounds__(512)
void scan_out(const u16* __restrict__ u, const float* __restrict__ plog,
              const float2* __restrict__ carry, u16* __restrict__ xr)
{
  const int j = threadIdx.x;
  const int c = blockIdx.x;
  const int b = blockIdx.y;
  float vv  = expf(plog[j]);
  float th  = expf(plog[512 + j]);
  float gm  = expf(plog[1024 + j]);
  float mag = expf(-vv);
  float lr = mag * cosf(th), li = mag * sinf(th);
  float2 h0 = carry[(size_t)(b * 32 + c) * 512 + j];
  float hr = h0.x, hi = h0.y;
  const u32* up = (const u32*)u;
  size_t uidx = (size_t)(b * 4096 + c * 128) * 512 + j;
  size_t xidx = (size_t)(b * 4096 + c * 128) * 1024 + j;
#pragma unroll 4
  for (int t = 0; t < 128; ++t) {
    u32 w = up[uidx]; uidx += 512;
    float ur = bflo(w), ui = bfhi(w);
    float nr = fmaf(lr, hr, fmaf(-li, hi, ur));
    float ni2 = fmaf(lr, hi, fmaf(li, hr, ui));
    hr = nr; hi = ni2;
    xr[xidx]       = f2bf(gm * hr);
    xr[xidx + 512] = f2bf(gm * hi);
    xidx += 1024;
  }
}

// ---------------- launch ----------------
// Shapes: B=8, L=4096, D=512; M=32768.
// ws layout (bytes):
//   [0, 64MB)          : A_bf (first 32MB) ... later reused as xr_bf (64MB)
//   [64MB, 128MB)      : u_bf
//   then Wi_bf, Wo_bf, e, carry (1MB each)
extern "C" void kernel_launch(void* const* d_in, const int* in_sizes, int n_in,
                              void* d_out, int out_size, void* d_ws, size_t ws_size,
                              hipStream_t stream)
{
  (void)in_sizes; (void)n_in; (void)out_size; (void)ws_size;
  const float* inputs = (const float*)d_in[0];
  const float* Wi     = (const float*)d_in[1];
  const float* bi     = (const float*)d_in[2];
  const float* Wo     = (const float*)d_in[3];
  const float* bo     = (const float*)d_in[4];
  const float* plog   = (const float*)d_in[5];

  char* ws = (char*)d_ws;
  u16*    xrA   = (u16*)(ws);                        // A_bf then xr_bf
  u16*    u_bf  = (u16*)(ws + 67108864ull);
  u16*    Wi_bf = (u16*)(ws + 134217728ull);
  u16*    Wo_bf = (u16*)(ws + 135266304ull);
  float2* e_b   = (float2*)(ws + 136314880ull);
  float2* ca_b  = (float2*)(ws + 137363456ull);

  // 1) convert to bf16
  conv_f32_bf16<<<16384, 256, 0, stream>>>(inputs, xrA, 4194304);   // 16.78M elems
  conv_f32_bf16<<<512,   256, 0, stream>>>(Wi, Wi_bf, 131072);
  conv_f32_bf16<<<512,   256, 0, stream>>>(Wo, Wo_bf, 131072);

  // 2) u = X @ Wi^T + bi   (M=32768, N=1024, K=512), bf16 out
  gemm_bt<1, 0><<<dim3(256, 8), 256, 0, stream>>>(xrA, Wi_bf, bi, u_bf,
                                                  32768, 1024, 512);

  // 3) chunked complex prefix scan + gamma, write xr (bf16) over A region
  scan_chunk_end<<<dim3(32, 8), 512, 0, stream>>>(u_bf, plog, e_b);
  scan_carry<<<8, 512, 0, stream>>>(e_b, plog, ca_b);
  scan_out<<<dim3(32, 8), 512, 0, stream>>>(u_bf, plog, ca_b, xrA);

  // 4) out = relu(xr @ Wo^T + bo)  (M=32768, N=512, K=1024), fp32 out
  gemm_bt<0, 1><<<dim3(256, 4), 256, 0, stream>>>(xrA, Wo_bf, bo, d_out,
                                                  32768, 512, 1024);
}

// Round 2
// 283.177 us; speedup vs baseline: 1.0103x; 1.0103x over previous
//
#include <hip/hip_runtime.h>
#include <cstdint>
#include <cstddef>

typedef unsigned short u16;
typedef unsigned int   u32;

typedef short bf16x8 __attribute__((ext_vector_type(8)));
typedef float f32x4  __attribute__((ext_vector_type(4)));

// ---------------- helpers ----------------
__device__ __forceinline__ u16 f2bf(float f) {   // RNE f32 -> bf16
  u32 u = __float_as_uint(f);
  u += 0x7fffu + ((u >> 16) & 1u);
  return (u16)(u >> 16);
}
__device__ __forceinline__ float bflo(u32 w) { return __uint_as_float((w & 0xffffu) << 16); }
__device__ __forceinline__ float bfhi(u32 w) { return __uint_as_float(w & 0xffff0000u); }

#define GLB_AS(p) ((const __attribute__((address_space(1))) void*)(p))
#define LDS_AS(p) ((__attribute__((address_space(3))) void*)(p))

// ---------------- f32 -> bf16 convert (4 elems/thread) ----------------
__global__ __launch_bounds__(256) void conv_f32_bf16(const float* __restrict__ src,
                                                     u16* __restrict__ dst, int n4) {
  int i = blockIdx.x * 256 + threadIdx.x;
  if (i >= n4) return;
  float4 v = ((const float4*)src)[i];
  u32 lo = (u32)f2bf(v.x) | ((u32)f2bf(v.y) << 16);
  u32 hi = (u32)f2bf(v.z) | ((u32)f2bf(v.w) << 16);
  ((uint2*)dst)[i] = make_uint2(lo, hi);
}

// two tensors in one launch (both weights)
__global__ __launch_bounds__(256) void conv2_f32_bf16(const float* __restrict__ s1,
                                                      u16* __restrict__ d1,
                                                      const float* __restrict__ s2,
                                                      u16* __restrict__ d2, int n4each) {
  int i = blockIdx.x * 256 + threadIdx.x;
  const float* src = s1; u16* dst = d1;
  if (i >= n4each) { i -= n4each; src = s2; dst = d2; }
  if (i >= n4each) return;
  float4 v = ((const float4*)src)[i];
  u32 lo = (u32)f2bf(v.x) | ((u32)f2bf(v.y) << 16);
  u32 hi = (u32)f2bf(v.z) | ((u32)f2bf(v.w) << 16);
  ((uint2*)dst)[i] = make_uint2(lo, hi);
}

// ---------------- bf16 GEMM: C[m,n] = sum_k A[m,k] * W[n,k] (+bias, opt relu)
// A: M x K row-major bf16; W: N x K row-major bf16 (i.e. B^T form).
// Tiles: BM=BN=128, BK=32. 256 threads = 4 waves in 2x2, each wave 64x64 (4x4
// MFMA 16x16x32 tiles). Staging via global_load_lds width=16 into XOR-swizzled
// 16B granules.
//
// Swizzle (R2 fix): granule g holds (row = g>>2, k8 = (g&3) ^ ((row>>1)&3)).
// Fragment read for (m, q): granule = m*4 + (q ^ ((m>>1)&3)).
//   g mod 8 = 4*(m&1) + (q ^ ((m>>1)&3)) -> over 16 consecutive m (fixed q)
//   all 8 bank-quads hit exactly 2x => 2-way aliasing, which is free (m136).
//   (Old swizzle used (m&3): only 4 of 8 quads -> 4-way conflict, the measured
//    4.19M SQ_LDS_BANK_CONFLICT = 4 cyc/read.)
template<int OUT_BF16, int RELU>
__global__ __launch_bounds__(256)
void gemm_bt(const u16* __restrict__ A, const u16* __restrict__ Bw,
             const float* __restrict__ bias, void* __restrict__ Cout,
             int M, int N, int K)
{
  __shared__ __align__(16) u16 As[128 * 32];
  __shared__ __align__(16) u16 Bs[128 * 32];

  const int tid  = threadIdx.x;
  const int lane = tid & 63;
  const int wave = tid >> 6;
  const int m0 = blockIdx.x * 128;
  const int n0 = blockIdx.y * 128;
  const int wm = (wave & 1) * 64;
  const int wn = (wave >> 1) * 64;

  f32x4 acc[4][4];
#pragma unroll
  for (int i = 0; i < 4; ++i)
#pragma unroll
    for (int j = 0; j < 4; ++j) acc[i][j] = f32x4{0.f, 0.f, 0.f, 0.f};

  // staging granules: 512 per tile, 256 threads -> 2 passes each for A and B.
  const int g0 = tid;        // pass 0
  const int g1 = 256 + tid;  // pass 1
  const int r0 = g0 >> 2, c0 = ((((g0 & 3) ^ ((r0 >> 1) & 3))) << 3);
  const int r1 = g1 >> 2, c1 = ((((g1 & 3) ^ ((r1 >> 1) & 3))) << 3);
  const u16* Asrc0 = A  + (size_t)(m0 + r0) * K + c0;
  const u16* Asrc1 = A  + (size_t)(m0 + r1) * K + c1;
  const u16* Bsrc0 = Bw + (size_t)(n0 + r0) * K + c0;
  const u16* Bsrc1 = Bw + (size_t)(n0 + r1) * K + c1;
  // wave-uniform LDS bases (HW adds lane*16)
  u16* ldsA0 = &As[(0 * 256 + wave * 64) * 8];
  u16* ldsA1 = &As[(1 * 256 + wave * 64) * 8];
  u16* ldsB0 = &Bs[(0 * 256 + wave * 64) * 8];
  u16* ldsB1 = &Bs[(1 * 256 + wave * 64) * 8];

  // fragment granule offsets (in u16 units)
  const int fm = lane & 15;
  const int q  = lane >> 4;
  int aoff[4], boff[4];
#pragma unroll
  for (int i = 0; i < 4; ++i) {
    int ml = wm + i * 16 + fm;
    aoff[i] = (ml * 4 + (q ^ ((ml >> 1) & 3))) * 8;
    int nl = wn + i * 16 + fm;
    boff[i] = (nl * 4 + (q ^ ((nl >> 1) & 3))) * 8;
  }

  for (int k0 = 0; k0 < K; k0 += 32) {
    __builtin_amdgcn_global_load_lds(GLB_AS(Asrc0 + k0), LDS_AS(ldsA0), 16, 0, 0);
    __builtin_amdgcn_global_load_lds(GLB_AS(Asrc1 + k0), LDS_AS(ldsA1), 16, 0, 0);
    __builtin_amdgcn_global_load_lds(GLB_AS(Bsrc0 + k0), LDS_AS(ldsB0), 16, 0, 0);
    __builtin_amdgcn_global_load_lds(GLB_AS(Bsrc1 + k0), LDS_AS(ldsB1), 16, 0, 0);
    __syncthreads();  // drains vmcnt -> tile visible

    bf16x8 af[4], bfr[4];
#pragma unroll
    for (int i = 0; i < 4; ++i) af[i]  = *(const bf16x8*)&As[aoff[i]];
#pragma unroll
    for (int i = 0; i < 4; ++i) bfr[i] = *(const bf16x8*)&Bs[boff[i]];
#pragma unroll
    for (int mi = 0; mi < 4; ++mi)
#pragma unroll
      for (int ni = 0; ni < 4; ++ni)
        acc[mi][ni] = __builtin_amdgcn_mfma_f32_16x16x32_bf16(af[mi], bfr[ni],
                                                              acc[mi][ni], 0, 0, 0);
    __syncthreads();  // all reads done before next-tile DMA overwrites
  }

  // epilogue: C/D layout col=lane&15, row=(lane>>4)*4+reg
  const int colL = lane & 15;
  const int rowQ = (lane >> 4) * 4;
#pragma unroll
  for (int mi = 0; mi < 4; ++mi) {
#pragma unroll
    for (int ni = 0; ni < 4; ++ni) {
      int col  = n0 + wn + ni * 16 + colL;
      int rowb = m0 + wm + mi * 16 + rowQ;
      float bv = bias[col];
#pragma unroll
      for (int r = 0; r < 4; ++r) {
        float v = acc[mi][ni][r] + bv;
        if (RELU) v = fmaxf(v, 0.f);
        size_t idx = (size_t)(rowb + r) * N + col;
        if (OUT_BF16) ((u16*)Cout)[idx] = f2bf(v);
        else          ((float*)Cout)[idx] = v;
      }
    }
  }
}

// ---------------- scan pass 1: per-chunk end state ----------------
__global__ __launch_bounds__(512)
void scan_chunk_end(const u16* __restrict__ u, const float* __restrict__ plog,
                    float2* __restrict__ e)
{
  const int j = threadIdx.x;   // channel 0..511
  const int c = blockIdx.x;    // chunk 0..31
  const int b = blockIdx.y;    // batch 0..7
  float vv  = expf(plog[j]);
  float th  = expf(plog[512 + j]);
  float mag = expf(-vv);
  float lr = mag * cosf(th), li = mag * sinf(th);
  const u32* up = (const u32*)u;
  size_t idx = (size_t)(b * 4096 + c * 128) * 512 + j;
  float hr = 0.f, hi = 0.f;
#pragma unroll 8
  for (int t = 0; t < 128; ++t) {
    u32 w = up[idx]; idx += 512;
    float ur = bflo(w), ui = bfhi(w);
    float nr = fmaf(lr, hr, fmaf(-li, hi, ur));
    float ni2 = fmaf(lr, hi, fmaf(li, hr, ui));
    hr = nr; hi = ni2;
  }
  e[(size_t)(b * 32 + c) * 512 + j] = make_float2(hr, hi);
}

// ---------------- scan pass 2: carries across chunks ----------------
__global__ __launch_bounds__(512)
void scan_carry(const float2* __restrict__ e, const float* __restrict__ plog,
                float2* __restrict__ carry)
{
  const int j = threadIdx.x;
  const int b = blockIdx.x;
  float vv = expf(plog[j]);
  float th = expf(plog[512 + j]);
  float mag = expf(-128.f * vv);
  float a = 128.f * th;
  float lr = mag * cosf(a), li = mag * sinf(a);  // lambda^128
  float Hr = 0.f, Hi = 0.f;
  for (int c = 0; c < 32; ++c) {
    size_t o = (size_t)(b * 32 + c) * 512 + j;
    carry[o] = make_float2(Hr, Hi);
    float2 ec = e[o];
    float nr = fmaf(lr, Hr, fmaf(-li, Hi, ec.x));
    float ni2 = fmaf(lr, Hi, fmaf(li, Hr, ec.y));
    Hr = nr; Hi = ni2;
  }
}

// ---------------- scan pass 3: recompute with carry, write xr (bf16) --------
__global__ __launch_bounds__(512)
void scan_out(const u16* __restrict__ u, const float* __restrict__ plog,
              const float2* __restrict__ carry, u16* __restrict__ xr)
{
  const int j = threadIdx.x;
  const int c = blockIdx.x;
  const int b = blockIdx.y;
  float vv  = expf(plog[j]);
  float th  = expf(plog[512 + j]);
  float gm  = expf(plog[1024 + j]);
  float mag = expf(-vv);
  float lr = mag * cosf(th), li = mag * sinf(th);
  float2 h0 = carry[(size_t)(b * 32 + c) * 512 + j];
  float hr = h0.x, hi = h0.y;
  const u32* up = (const u32*)u;
  size_t uidx = (size_t)(b * 4096 + c * 128) * 512 + j;
  size_t xidx = (size_t)(b * 4096 + c * 128) * 1024 + j;
#pragma unroll 4
  for (int t = 0; t < 128; ++t) {
    u32 w = up[uidx]; uidx += 512;
    float ur = bflo(w), ui = bfhi(w);
    float nr = fmaf(lr, hr, fmaf(-li, hi, ur));
    float ni2 = fmaf(lr, hi, fmaf(li, hr, ui));
    hr = nr; hi = ni2;
    xr[xidx]       = f2bf(gm * hr);
    xr[xidx + 512] = f2bf(gm * hi);
    xidx += 1024;
  }
}

// ---------------- launch ----------------
extern "C" void kernel_launch(void* const* d_in, const int* in_sizes, int n_in,
                              void* d_out, int out_size, void* d_ws, size_t ws_size,
                              hipStream_t stream)
{
  (void)in_sizes; (void)n_in; (void)out_size; (void)ws_size;
  const float* inputs = (const float*)d_in[0];
  const float* Wi     = (const float*)d_in[1];
  const float* bi     = (const float*)d_in[2];
  const float* Wo     = (const float*)d_in[3];
  const float* bo     = (const float*)d_in[4];
  const float* plog   = (const float*)d_in[5];

  char* ws = (char*)d_ws;
  u16*    xrA   = (u16*)(ws);                        // A_bf then xr_bf
  u16*    u_bf  = (u16*)(ws + 67108864ull);
  u16*    Wi_bf = (u16*)(ws + 134217728ull);
  u16*    Wo_bf = (u16*)(ws + 135266304ull);
  float2* e_b   = (float2*)(ws + 136314880ull);
  float2* ca_b  = (float2*)(ws + 137363456ull);

  // 1) convert to bf16
  conv_f32_bf16<<<16384, 256, 0, stream>>>(inputs, xrA, 4194304);   // 16.78M elems
  conv2_f32_bf16<<<1024, 256, 0, stream>>>(Wi, Wi_bf, Wo, Wo_bf, 131072);

  // 2) u = X @ Wi^T + bi   (M=32768, N=1024, K=512), bf16 out
  gemm_bt<1, 0><<<dim3(256, 8), 256, 0, stream>>>(xrA, Wi_bf, bi, u_bf,
                                                  32768, 1024, 512);

  // 3) chunked complex prefix scan + gamma, write xr (bf16) over A region
  scan_chunk_end<<<dim3(32, 8), 512, 0, stream>>>(u_bf, plog, e_b);
  scan_carry<<<8, 512, 0, stream>>>(e_b, plog, ca_b);
  scan_out<<<dim3(32, 8), 512, 0, stream>>>(u_bf, plog, ca_b, xrA);

  // 4) out = relu(xr @ Wo^T + bo)  (M=32768, N=512, K=1024), fp32 out
  gemm_bt<0, 1><<<dim3(256, 4), 256, 0, stream>>>(xrA, Wo_bf, bo, d_out,
                                                  32768, 512, 1024);
}